// Round 7
// baseline (253.473 us; speedup 1.0000x reference)
//
#include <hip/hip_runtime.h>

// Multi-head attention, B=2 S=2048 D=768 H=12 DK=64. I/O fp32, internal bf16 MFMA.
// GEMMs: m97-style async global_load_lds K-loop, 128x128 tile; QKV epilogue via
// LDS C-bounce (16B/lane stores). attn: 64-query blocks, waves split 2x2 over
// (q-half, key-half) for 3 blocks/CU; S^T = K.Q^T 32x32x16 so exp(S^T) regs feed
// P.V directly as 32x32x8 A-operand; register-prefetch K/V pipeline; partial O/l
// combined across key-half wave pairs through LDS once at the end.

#define H_ 12
#define DK_ 64
#define B_DIM 2
#define SEQ 2048
#define DM 768
#define MROWS 4096
#define PER_IN ((size_t)MROWS * DM)

typedef short bf16x8 __attribute__((ext_vector_type(8)));
typedef short bf16x4 __attribute__((ext_vector_type(4)));
typedef float f32x4 __attribute__((ext_vector_type(4)));
typedef float f32x16 __attribute__((ext_vector_type(16)));

__device__ inline unsigned short f2bf(float f) {
    union { float f; unsigned int i; } x; x.f = f;
    unsigned int r = x.i + 0x7fff + ((x.i >> 16) & 1); // RNE
    return (unsigned short)(r >> 16);
}

__device__ inline unsigned pack2bf(float lo, float hi) {
#if __has_builtin(__builtin_amdgcn_cvt_pk_bf16_f32)
    auto v = __builtin_amdgcn_cvt_pk_bf16_f32(lo, hi);
    return __builtin_bit_cast(unsigned, v);
#else
    return (unsigned)f2bf(lo) | ((unsigned)f2bf(hi) << 16);
#endif
}

__device__ inline f32x16 mfma32x8(bf16x4 a, bf16x4 b, f32x16 c) {
#if __has_builtin(__builtin_amdgcn_mfma_f32_32x32x8bf16_1k)
    return __builtin_amdgcn_mfma_f32_32x32x8bf16_1k(a, b, c, 0, 0, 0);
#else
    asm("v_mfma_f32_32x32x8_bf16 %0, %1, %2, %0" : "+v"(c) : "v"(a), "v"(b));
    return c;
#endif
}

// async 16B/lane global->LDS; ldsbase must be wave-uniform (HW adds lane*16B)
__device__ inline void gload_lds16(const unsigned short* g, unsigned short* ldsbase,
                                   int lane) {
#if __has_builtin(__builtin_amdgcn_global_load_lds)
    __builtin_amdgcn_global_load_lds(
        (const __attribute__((address_space(1))) unsigned int*)g,
        (__attribute__((address_space(3))) unsigned int*)ldsbase, 16, 0, 0);
#else
    *(uint4*)(ldsbase + 8 * lane) = *(const uint4*)g;
#endif
}

// -------- fp32 -> bf16 convert, 3 buffers in one launch --------
__global__ void cvt3(const float* __restrict__ a, const float* __restrict__ b,
                     const float* __restrict__ c,
                     unsigned short* __restrict__ oa, unsigned short* __restrict__ ob,
                     unsigned short* __restrict__ oc) {
    const float* src = blockIdx.y == 0 ? a : (blockIdx.y == 1 ? b : c);
    unsigned short* dst = blockIdx.y == 0 ? oa : (blockIdx.y == 1 ? ob : oc);
    size_t i = ((size_t)blockIdx.x * 256 + threadIdx.x) * 4;
    float4 f = *(const float4*)(src + i);
    ushort4 u;
    u.x = f2bf(f.x); u.y = f2bf(f.y); u.z = f2bf(f.z); u.w = f2bf(f.w);
    *(ushort4*)(dst + i) = u;
}

// -------- 4 weight transposes in one launch: Wt[n][k] = bf16(W[k][n]) --------
__global__ void transpose4(const float* __restrict__ w0, const float* __restrict__ w1,
                           const float* __restrict__ w2, const float* __restrict__ w3,
                           unsigned short* __restrict__ outbase) {
    const float* in = blockIdx.z == 0 ? w0 : (blockIdx.z == 1 ? w1 : (blockIdx.z == 2 ? w2 : w3));
    unsigned short* out = outbase + (size_t)blockIdx.z * DM * DM;
    __shared__ unsigned short t[32][33];
    int x = threadIdx.x, y = threadIdx.y; // 32 x 8
    int k0 = blockIdx.x * 32, n0 = blockIdx.y * 32;
#pragma unroll
    for (int i = 0; i < 32; i += 8)
        t[y + i][x] = f2bf(in[(size_t)(k0 + y + i) * DM + n0 + x]);
    __syncthreads();
#pragma unroll
    for (int i = 0; i < 32; i += 8)
        out[(size_t)(n0 + y + i) * DM + k0 + x] = t[x][y + i];
}

// -------- V head-tile transpose: (bh, s, d) -> (bh, d, s), 64x64 LDS tiles ----
__global__ __launch_bounds__(256) void transposeV(const unsigned short* __restrict__ Vn,
                                                  unsigned short* __restrict__ Vt) {
    __shared__ unsigned short Tl[64][72];
    int tid = threadIdx.x;
    int s0 = blockIdx.x * 64, bh = blockIdx.y;
    int row = tid >> 2, cb = (tid & 3) * 16;
    const unsigned short* g = Vn + ((size_t)bh * SEQ + s0 + row) * DK_ + cb;
    uint4 a = *(const uint4*)g;
    uint4 b = *(const uint4*)(g + 8);
    unsigned short v[16];
    *(uint4*)&v[0] = a;
    *(uint4*)&v[8] = b;
#pragma unroll
    for (int j = 0; j < 16; j++)
        Tl[cb + j][row] = v[j];
    __syncthreads();
    uint4 o0 = *(const uint4*)&Tl[row][cb];
    uint4 o1 = *(const uint4*)&Tl[row][cb + 8];
    unsigned short* out = Vt + ((size_t)bh * DK_ + row) * SEQ + s0 + cb;
    *(uint4*)out = o0;
    *(uint4*)(out + 8) = o1;
}

// ---------------- GEMM: C[m][n] = A[m][:] . Wt[n][:] + bias[n] ----------------
template <int QKV>
__global__ __launch_bounds__(256) void gemm128(
    const unsigned short* __restrict__ A0, const unsigned short* __restrict__ A1,
    const unsigned short* __restrict__ A2, const unsigned short* __restrict__ Wt,
    const float* __restrict__ bias0, const float* __restrict__ bias1,
    const float* __restrict__ bias2,
    void* __restrict__ O0, void* __restrict__ O1, void* __restrict__ O2) {
    __shared__ unsigned short S[2][128][64]; // A=S[0], B=S[1]; no pad (load_lds)
    unsigned short (*Al)[64] = S[0];
    unsigned short (*Bl)[64] = S[1];
    const int K = DM;
    int tid = threadIdx.x;
    int wave = tid >> 6, lane = tid & 63, quad = lane >> 4, l15 = lane & 15;
    int wr = wave >> 1, wc = wave & 1;
    int m0 = blockIdx.x * 128, n0 = blockIdx.y * 128;
    int lrow = lane >> 3, lcol = (lane & 7) * 8;

    int mi = 0, nb0 = n0;
    const unsigned short* A = A0;
    const float* bias = bias0;
    void* O = O0;
    if constexpr (QKV) {
        mi = n0 >= 1536 ? 2 : (n0 >= 768 ? 1 : 0);
        nb0 = n0 - mi * 768;
        A = mi == 0 ? A0 : (mi == 1 ? A1 : A2);
        bias = mi == 0 ? bias0 : (mi == 1 ? bias1 : bias2);
        O = mi == 0 ? O0 : (mi == 1 ? O1 : O2);
    }

    f32x4 acc[4][4];
#pragma unroll
    for (int i = 0; i < 4; i++)
#pragma unroll
        for (int j = 0; j < 4; j++)
#pragma unroll
            for (int r = 0; r < 4; r++) acc[i][j][r] = 0.f;

    const unsigned short* gA = A + (size_t)(m0 + 32 * wave + lrow) * K + lcol;
    const unsigned short* gB = Wt + (size_t)(n0 + 32 * wave + lrow) * K + lcol;

    for (int k0 = 0; k0 < K; k0 += 64) {
        __syncthreads();
#pragma unroll
        for (int c = 0; c < 4; c++) {
            gload_lds16(gA + (size_t)8 * c * K + k0, &Al[32 * wave + 8 * c][0], lane);
            gload_lds16(gB + (size_t)8 * c * K + k0, &Bl[32 * wave + 8 * c][0], lane);
        }
        __syncthreads();
#pragma unroll
        for (int ks = 0; ks < 64; ks += 32) {
            bf16x8 af[4], bfr[4];
#pragma unroll
            for (int i = 0; i < 4; i++)
                af[i] = *(const bf16x8*)&Al[64 * wr + 16 * i + l15][ks + 8 * quad];
#pragma unroll
            for (int j = 0; j < 4; j++)
                bfr[j] = *(const bf16x8*)&Bl[64 * wc + 16 * j + l15][ks + 8 * quad];
#pragma unroll
            for (int i = 0; i < 4; i++)
#pragma unroll
                for (int j = 0; j < 4; j++)
                    acc[i][j] = __builtin_amdgcn_mfma_f32_16x16x32_bf16(af[i], bfr[j], acc[i][j], 0, 0, 0);
        }
    }

    if constexpr (!QKV) {
#pragma unroll
        for (int j = 0; j < 4; j++) {
            int nn = nb0 + 64 * wc + 16 * j + l15;
            float bv = bias[nn];
#pragma unroll
            for (int i = 0; i < 4; i++)
#pragma unroll
                for (int r = 0; r < 4; r++) {
                    int m = m0 + 64 * wr + 16 * i + 4 * quad + r;
                    ((float*)O0)[(size_t)m * DM + nn] = acc[i][j][r] + bv;
                }
        }
    } else {
        __syncthreads();
        unsigned short (*Cl)[128] = (unsigned short(*)[128])S;
#pragma unroll
        for (int j = 0; j < 4; j++) {
            float bv = bias[nb0 + 64 * wc + 16 * j + l15];
#pragma unroll
            for (int i = 0; i < 4; i++)
#pragma unroll
                for (int r = 0; r < 4; r++)
                    Cl[64 * wr + 16 * i + 4 * quad + r][64 * wc + 16 * j + l15] =
                        f2bf(acc[i][j][r] + bv);
        }
        __syncthreads();
        int row = tid >> 1, half = tid & 1;
        int m = m0 + row;
        int b = m >> 11, s = m & 2047;
        int h = (nb0 + 64 * half) >> 6;
        unsigned short* og = (unsigned short*)O + ((size_t)(b * H_ + h) * SEQ + s) * DK_;
        const unsigned short* cr = &Cl[row][64 * half];
#pragma unroll
        for (int c = 0; c < 4; c++)
            *(uint4*)(og + 16 * c) = *(const uint4*)(cr + 16 * c);
#pragma unroll
        for (int c = 0; c < 4; c++)
            *(uint4*)(og + 16 * c + 8) = *(const uint4*)(cr + 16 * c + 8);
    }
}

// ---------------- flash attention: 64-query blocks, 2x2 wave split -------------
// Q,K: (b,h,s,d) bf16; Vt: (b,h,d,s) bf16; mask: (b,1,s) int32; ctx: (b,s,h*d) bf16
__global__ __launch_bounds__(256) void attn_fa(const unsigned short* __restrict__ Q,
                                               const unsigned short* __restrict__ Kh,
                                               const unsigned short* __restrict__ Vt,
                                               const int* __restrict__ mask,
                                               unsigned short* __restrict__ ctx) {
    __shared__ unsigned short Ql[64][72];
    __shared__ float mb[SEQ];
    __shared__ union {
        struct { unsigned short K[64][72]; unsigned short V[64][68]; } kv;
        struct { float Op[2][32][64]; float lp[2][32]; } ep;
    } S;
    int tid = threadIdx.x;
    int wave = tid >> 6, lane = tid & 63;
    int l31 = lane & 31, hi = lane >> 5;
    int qh = wave & 1, kh = wave >> 1; // q-half, key-half
    int bh = blockIdx.y, b = bh / H_, h = bh % H_;
    int q0 = blockIdx.x * 64;

    { // stage Q tile (64x64) once
        int row = tid >> 2, cb = (tid & 3) * 16;
        const unsigned short* gq = Q + ((size_t)bh * SEQ + q0 + row) * DK_ + cb;
        *(uint4*)&Ql[row][cb]     = *(const uint4*)gq;
        *(uint4*)&Ql[row][cb + 8] = *(const uint4*)(gq + 8);
    }
    { // mask -> additive bias in LDS (once per block)
        const int* mp = mask + (size_t)b * SEQ + tid * 8;
        int4 m0_ = *(const int4*)mp;
        int4 m1_ = *(const int4*)(mp + 4);
        float4 f0, f1;
        f0.x = m0_.x ? 0.f : -1e9f; f0.y = m0_.y ? 0.f : -1e9f;
        f0.z = m0_.z ? 0.f : -1e9f; f0.w = m0_.w ? 0.f : -1e9f;
        f1.x = m1_.x ? 0.f : -1e9f; f1.y = m1_.y ? 0.f : -1e9f;
        f1.z = m1_.z ? 0.f : -1e9f; f1.w = m1_.w ? 0.f : -1e9f;
        *(float4*)&mb[tid * 8] = f0;
        *(float4*)&mb[tid * 8 + 4] = f1;
    }
    __syncthreads(); // Ql/mb staged

    // loop-invariant Q fragments (queries 32*qh + l31)
    bf16x8 qf[4];
#pragma unroll
    for (int c = 0; c < 4; c++)
        qf[c] = *(const bf16x8*)&Ql[32 * qh + l31][16 * c + 8 * hi];

    float lrow = 0.f; // per-lane (q = l31) partial row sum over this wave's keys
    f32x16 o[2][2];   // [d-half][ilp]; summed at end
#pragma unroll
    for (int dt = 0; dt < 2; dt++)
#pragma unroll
        for (int p = 0; p < 2; p++)
#pragma unroll
            for (int r = 0; r < 16; r++) o[dt][p][r] = 0.f;

    int krow = tid >> 2, kcb = (tid & 3) * 16;
    const unsigned short* gk = Kh + ((size_t)bh * SEQ + krow) * DK_ + kcb;
    const unsigned short* gv = Vt + ((size_t)bh * DK_ + krow) * SEQ + kcb;

    // prefetch iter 0
    uint4 kr0 = *(const uint4*)gk, kr1 = *(const uint4*)(gk + 8);
    uint4 vr0 = *(const uint4*)gv, vr1 = *(const uint4*)(gv + 8);

    for (int kt = 0; kt < SEQ / 64; kt++) {
        __syncthreads(); // prev iter's K/V LDS reads done
        *(uint4*)&S.kv.K[krow][kcb]     = kr0;
        *(uint4*)&S.kv.K[krow][kcb + 8] = kr1;
        *(uint4*)&S.kv.V[krow][kcb]     = vr0;
        *(uint4*)&S.kv.V[krow][kcb + 8] = vr1;
        __syncthreads(); // tiles visible
        if (kt + 1 < SEQ / 64) { // prefetch next (latency hidden under compute)
            gk += (size_t)64 * DK_;
            gv += 64;
            kr0 = *(const uint4*)gk; kr1 = *(const uint4*)(gk + 8);
            vr0 = *(const uint4*)gv; vr1 = *(const uint4*)(gv + 8);
        }

        int kbase = 64 * kt + 32 * kh;
        // S^T = K.Q^T + maskbias (32 keys x 32 queries for this wave)
        f32x16 sT;
#pragma unroll
        for (int c = 0; c < 4; c++) {
            f32x4 mv = *(const f32x4*)&mb[kbase + 8 * c + 4 * hi];
#pragma unroll
            for (int j = 0; j < 4; j++) sT[4 * c + j] = mv[j];
        }
#pragma unroll
        for (int c = 0; c < 4; c++) {
            bf16x8 kf = *(const bf16x8*)&S.kv.K[32 * kh + l31][16 * c + 8 * hi];
            sT = __builtin_amdgcn_mfma_f32_32x32x16_bf16(kf, qf[c], sT, 0, 0, 0);
        }

        // p = exp(s/8): regs ARE the A-operand of the 32x32x8 PV MFMA
        bf16x4 pfrag[4];
#pragma unroll
        for (int c = 0; c < 4; c++) {
            float p0 = __expf(sT[4 * c + 0] * 0.125f);
            float p1 = __expf(sT[4 * c + 1] * 0.125f);
            float p2 = __expf(sT[4 * c + 2] * 0.125f);
            float p3 = __expf(sT[4 * c + 3] * 0.125f);
            lrow += (p0 + p1) + (p2 + p3);
            union { unsigned u[2]; bf16x4 v; } pk;
            pk.u[0] = pack2bf(p0, p1);
            pk.u[1] = pack2bf(p2, p3);
            pfrag[c] = pk.v;
        }

        // O[q][d] += P.V over this wave's 32 keys
#pragma unroll
        for (int dt = 0; dt < 2; dt++)
#pragma unroll
            for (int c = 0; c < 4; c++) {
                bf16x4 vf = *(const bf16x4*)&S.kv.V[32 * dt + l31][32 * kh + 8 * c + 4 * hi];
                o[dt][c & 1] = mfma32x8(pfrag[c], vf, o[dt][c & 1]);
            }
    }

    // combine across key-half wave pairs via LDS, normalize, store
    __syncthreads(); // all K/V LDS reads done; safe to overlay epilogue scratch
    lrow += __shfl_xor(lrow, 32); // both hi-halves now hold full partial for q=l31
    if (kh == 1) {
#pragma unroll
        for (int dt = 0; dt < 2; dt++)
#pragma unroll
            for (int r = 0; r < 16; r++) {
                int qrl = (r & 3) + 8 * (r >> 2) + 4 * hi;
                S.ep.Op[qh][qrl][32 * dt + l31] = o[dt][0][r] + o[dt][1][r];
            }
        if (hi == 0) S.ep.lp[qh][l31] = lrow;
    }
    __syncthreads();
    if (kh == 0) {
        float l = lrow + S.ep.lp[qh][l31];
        float inv = l > 0.f ? 1.f / l : 0.f;
#pragma unroll
        for (int r = 0; r < 16; r++) {
            int qrl = (r & 3) + 8 * (r >> 2) + 4 * hi;
            float invr = __shfl(inv, qrl); // inv lives at lane q
            int qg = q0 + 32 * qh + qrl;
            size_t base = ((size_t)b * SEQ + qg) * DM + h * DK_;
            float v0 = o[0][0][r] + o[0][1][r] + S.ep.Op[qh][qrl][l31];
            float v1 = o[1][0][r] + o[1][1][r] + S.ep.Op[qh][qrl][32 + l31];
            ctx[base + l31]      = f2bf(v0 * invr);
            ctx[base + 32 + l31] = f2bf(v1 * invr);
        }
    }
}

extern "C" void kernel_launch(void* const* d_in, const int* in_sizes, int n_in,
                              void* d_out, int out_size, void* d_ws, size_t ws_size,
                              hipStream_t stream) {
    const float* q  = (const float*)d_in[0];
    const float* k  = (const float*)d_in[1];
    const float* v  = (const float*)d_in[2];
    const float* Wq = (const float*)d_in[3];
    const float* bq = (const float*)d_in[4];
    const float* Wk = (const float*)d_in[5];
    const float* bk = (const float*)d_in[6];
    const float* Wv = (const float*)d_in[7];
    const float* bv = (const float*)d_in[8];
    const float* Wo = (const float*)d_in[9];
    const float* bo = (const float*)d_in[10];
    const int* mask = (const int*)d_in[11];

    unsigned short* ws = (unsigned short*)d_ws;
    unsigned short* qb = ws;
    unsigned short* kb = ws + PER_IN;
    unsigned short* vb = ws + 2 * PER_IN;
    unsigned short* Qh = ws + 3 * PER_IN;
    unsigned short* Kh = ws + 4 * PER_IN;
    unsigned short* Vhn = ws + 5 * PER_IN;
    unsigned short* WtQKV = ws + 6 * PER_IN;
    unsigned short* WtO = WtQKV + (size_t)3 * DM * DM;
    unsigned short* Vt = vb;  // vb dead after QKV GEMM
    unsigned short* ctx = qb; // qb dead after QKV GEMM

    cvt3<<<dim3(PER_IN / 1024, 3), 256, 0, stream>>>(q, k, v, qb, kb, vb);
    transpose4<<<dim3(DM / 32, DM / 32, 4), dim3(32, 8), 0, stream>>>(Wq, Wk, Wv, Wo, WtQKV);

    gemm128<1><<<dim3(MROWS / 128, 3 * DM / 128), 256, 0, stream>>>(
        qb, kb, vb, WtQKV, bq, bk, bv, Qh, Kh, Vhn);

    transposeV<<<dim3(SEQ / 64, B_DIM * H_), 256, 0, stream>>>(Vhn, Vt);

    attn_fa<<<dim3(SEQ / 64, B_DIM * H_), 256, 0, stream>>>(Qh, Kh, Vt, mask, ctx);

    gemm128<0><<<dim3(MROWS / 128, DM / 128), 256, 0, stream>>>(
        ctx, ctx, ctx, WtO, bo, bo, bo, d_out, d_out, d_out);
}

// Round 8
// 226.173 us; speedup vs baseline: 1.1207x; 1.1207x over previous
//
#include <hip/hip_runtime.h>

// Multi-head attention, B=2 S=2048 D=768 H=12 DK=64. I/O fp32, internal bf16 MFMA.
// GEMMs: m97-style async global_load_lds K-loop, 128x128 tile; QKV epilogue via
// LDS C-bounce. attn: 64-query blocks (768 blocks = 3/CU), waves split 2x2 over
// (q-half, key-half); S^T = K.Q^T 32x32x16 so exp(S^T) regs feed P.V directly as
// 32x32x8 A-operand; register K/V prefetch. Round-7 lesson: shared-memory UNION
// dropped base alignment to 4B -> ds_read_b128 split into b32s -> 18.9M bank
// conflicts. All LDS arrays standalone + __align__(16), strides 72 (b128 rows)
// and 68 (V b64 rows) are conflict-free per phase.

#define H_ 12
#define DK_ 64
#define B_DIM 2
#define SEQ 2048
#define DM 768
#define MROWS 4096
#define PER_IN ((size_t)MROWS * DM)

typedef short bf16x8 __attribute__((ext_vector_type(8)));
typedef short bf16x4 __attribute__((ext_vector_type(4)));
typedef float f32x4 __attribute__((ext_vector_type(4)));
typedef float f32x16 __attribute__((ext_vector_type(16)));

__device__ inline unsigned short f2bf(float f) {
    union { float f; unsigned int i; } x; x.f = f;
    unsigned int r = x.i + 0x7fff + ((x.i >> 16) & 1); // RNE
    return (unsigned short)(r >> 16);
}

__device__ inline unsigned pack2bf(float lo, float hi) {
#if __has_builtin(__builtin_amdgcn_cvt_pk_bf16_f32)
    auto v = __builtin_amdgcn_cvt_pk_bf16_f32(lo, hi);
    return __builtin_bit_cast(unsigned, v);
#else
    return (unsigned)f2bf(lo) | ((unsigned)f2bf(hi) << 16);
#endif
}

__device__ inline f32x16 mfma32x8(bf16x4 a, bf16x4 b, f32x16 c) {
#if __has_builtin(__builtin_amdgcn_mfma_f32_32x32x8bf16_1k)
    return __builtin_amdgcn_mfma_f32_32x32x8bf16_1k(a, b, c, 0, 0, 0);
#else
    asm("v_mfma_f32_32x32x8_bf16 %0, %1, %2, %0" : "+v"(c) : "v"(a), "v"(b));
    return c;
#endif
}

// async 16B/lane global->LDS; ldsbase must be wave-uniform (HW adds lane*16B)
__device__ inline void gload_lds16(const unsigned short* g, unsigned short* ldsbase,
                                   int lane) {
#if __has_builtin(__builtin_amdgcn_global_load_lds)
    __builtin_amdgcn_global_load_lds(
        (const __attribute__((address_space(1))) unsigned int*)g,
        (__attribute__((address_space(3))) unsigned int*)ldsbase, 16, 0, 0);
#else
    *(uint4*)(ldsbase + 8 * lane) = *(const uint4*)g;
#endif
}

// -------- fp32 -> bf16 convert, 3 buffers in one launch --------
__global__ void cvt3(const float* __restrict__ a, const float* __restrict__ b,
                     const float* __restrict__ c,
                     unsigned short* __restrict__ oa, unsigned short* __restrict__ ob,
                     unsigned short* __restrict__ oc) {
    const float* src = blockIdx.y == 0 ? a : (blockIdx.y == 1 ? b : c);
    unsigned short* dst = blockIdx.y == 0 ? oa : (blockIdx.y == 1 ? ob : oc);
    size_t i = ((size_t)blockIdx.x * 256 + threadIdx.x) * 4;
    float4 f = *(const float4*)(src + i);
    ushort4 u;
    u.x = f2bf(f.x); u.y = f2bf(f.y); u.z = f2bf(f.z); u.w = f2bf(f.w);
    *(ushort4*)(dst + i) = u;
}

// -------- 4 weight transposes in one launch: Wt[n][k] = bf16(W[k][n]) --------
__global__ void transpose4(const float* __restrict__ w0, const float* __restrict__ w1,
                           const float* __restrict__ w2, const float* __restrict__ w3,
                           unsigned short* __restrict__ outbase) {
    const float* in = blockIdx.z == 0 ? w0 : (blockIdx.z == 1 ? w1 : (blockIdx.z == 2 ? w2 : w3));
    unsigned short* out = outbase + (size_t)blockIdx.z * DM * DM;
    __shared__ unsigned short t[32][33];
    int x = threadIdx.x, y = threadIdx.y; // 32 x 8
    int k0 = blockIdx.x * 32, n0 = blockIdx.y * 32;
#pragma unroll
    for (int i = 0; i < 32; i += 8)
        t[y + i][x] = f2bf(in[(size_t)(k0 + y + i) * DM + n0 + x]);
    __syncthreads();
#pragma unroll
    for (int i = 0; i < 32; i += 8)
        out[(size_t)(n0 + y + i) * DM + k0 + x] = t[x][y + i];
}

// -------- V head-tile transpose: (bh, s, d) -> (bh, d, s), 64x64 LDS tiles ----
__global__ __launch_bounds__(256) void transposeV(const unsigned short* __restrict__ Vn,
                                                  unsigned short* __restrict__ Vt) {
    __shared__ unsigned short Tl[64][72];
    int tid = threadIdx.x;
    int s0 = blockIdx.x * 64, bh = blockIdx.y;
    int row = tid >> 2, cb = (tid & 3) * 16;
    const unsigned short* g = Vn + ((size_t)bh * SEQ + s0 + row) * DK_ + cb;
    uint4 a = *(const uint4*)g;
    uint4 b = *(const uint4*)(g + 8);
    unsigned short v[16];
    *(uint4*)&v[0] = a;
    *(uint4*)&v[8] = b;
#pragma unroll
    for (int j = 0; j < 16; j++)
        Tl[cb + j][row] = v[j];
    __syncthreads();
    uint4 o0 = *(const uint4*)&Tl[row][cb];
    uint4 o1 = *(const uint4*)&Tl[row][cb + 8];
    unsigned short* out = Vt + ((size_t)bh * DK_ + row) * SEQ + s0 + cb;
    *(uint4*)out = o0;
    *(uint4*)(out + 8) = o1;
}

// ---------------- GEMM: C[m][n] = A[m][:] . Wt[n][:] + bias[n] ----------------
template <int QKV>
__global__ __launch_bounds__(256) void gemm128(
    const unsigned short* __restrict__ A0, const unsigned short* __restrict__ A1,
    const unsigned short* __restrict__ A2, const unsigned short* __restrict__ Wt,
    const float* __restrict__ bias0, const float* __restrict__ bias1,
    const float* __restrict__ bias2,
    void* __restrict__ O0, void* __restrict__ O1, void* __restrict__ O2) {
    __shared__ unsigned short S[2][128][64]; // A=S[0], B=S[1]; no pad (load_lds)
    unsigned short (*Al)[64] = S[0];
    unsigned short (*Bl)[64] = S[1];
    const int K = DM;
    int tid = threadIdx.x;
    int wave = tid >> 6, lane = tid & 63, quad = lane >> 4, l15 = lane & 15;
    int wr = wave >> 1, wc = wave & 1;
    int m0 = blockIdx.x * 128, n0 = blockIdx.y * 128;
    int lrow = lane >> 3, lcol = (lane & 7) * 8;

    int mi = 0, nb0 = n0;
    const unsigned short* A = A0;
    const float* bias = bias0;
    void* O = O0;
    if constexpr (QKV) {
        mi = n0 >= 1536 ? 2 : (n0 >= 768 ? 1 : 0);
        nb0 = n0 - mi * 768;
        A = mi == 0 ? A0 : (mi == 1 ? A1 : A2);
        bias = mi == 0 ? bias0 : (mi == 1 ? bias1 : bias2);
        O = mi == 0 ? O0 : (mi == 1 ? O1 : O2);
    }

    f32x4 acc[4][4];
#pragma unroll
    for (int i = 0; i < 4; i++)
#pragma unroll
        for (int j = 0; j < 4; j++)
#pragma unroll
            for (int r = 0; r < 4; r++) acc[i][j][r] = 0.f;

    const unsigned short* gA = A + (size_t)(m0 + 32 * wave + lrow) * K + lcol;
    const unsigned short* gB = Wt + (size_t)(n0 + 32 * wave + lrow) * K + lcol;

    for (int k0 = 0; k0 < K; k0 += 64) {
        __syncthreads();
#pragma unroll
        for (int c = 0; c < 4; c++) {
            gload_lds16(gA + (size_t)8 * c * K + k0, &Al[32 * wave + 8 * c][0], lane);
            gload_lds16(gB + (size_t)8 * c * K + k0, &Bl[32 * wave + 8 * c][0], lane);
        }
        __syncthreads();
#pragma unroll
        for (int ks = 0; ks < 64; ks += 32) {
            bf16x8 af[4], bfr[4];
#pragma unroll
            for (int i = 0; i < 4; i++)
                af[i] = *(const bf16x8*)&Al[64 * wr + 16 * i + l15][ks + 8 * quad];
#pragma unroll
            for (int j = 0; j < 4; j++)
                bfr[j] = *(const bf16x8*)&Bl[64 * wc + 16 * j + l15][ks + 8 * quad];
#pragma unroll
            for (int i = 0; i < 4; i++)
#pragma unroll
                for (int j = 0; j < 4; j++)
                    acc[i][j] = __builtin_amdgcn_mfma_f32_16x16x32_bf16(af[i], bfr[j], acc[i][j], 0, 0, 0);
        }
    }

    if constexpr (!QKV) {
#pragma unroll
        for (int j = 0; j < 4; j++) {
            int nn = nb0 + 64 * wc + 16 * j + l15;
            float bv = bias[nn];
#pragma unroll
            for (int i = 0; i < 4; i++)
#pragma unroll
                for (int r = 0; r < 4; r++) {
                    int m = m0 + 64 * wr + 16 * i + 4 * quad + r;
                    ((float*)O0)[(size_t)m * DM + nn] = acc[i][j][r] + bv;
                }
        }
    } else {
        __syncthreads();
        unsigned short (*Cl)[128] = (unsigned short(*)[128])S;
#pragma unroll
        for (int j = 0; j < 4; j++) {
            float bv = bias[nb0 + 64 * wc + 16 * j + l15];
#pragma unroll
            for (int i = 0; i < 4; i++)
#pragma unroll
                for (int r = 0; r < 4; r++)
                    Cl[64 * wr + 16 * i + 4 * quad + r][64 * wc + 16 * j + l15] =
                        f2bf(acc[i][j][r] + bv);
        }
        __syncthreads();
        int row = tid >> 1, half = tid & 1;
        int m = m0 + row;
        int b = m >> 11, s = m & 2047;
        int h = (nb0 + 64 * half) >> 6;
        unsigned short* og = (unsigned short*)O + ((size_t)(b * H_ + h) * SEQ + s) * DK_;
        const unsigned short* cr = &Cl[row][64 * half];
#pragma unroll
        for (int c = 0; c < 4; c++)
            *(uint4*)(og + 16 * c) = *(const uint4*)(cr + 16 * c);
#pragma unroll
        for (int c = 0; c < 4; c++)
            *(uint4*)(og + 16 * c + 8) = *(const uint4*)(cr + 16 * c + 8);
    }
}

// ---------------- flash attention: 64-query blocks, 2x2 wave split -------------
// Q,K: (b,h,s,d) bf16; Vt: (b,h,d,s) bf16; mask: (b,1,s) int32; ctx: (b,s,h*d) bf16
__global__ __launch_bounds__(256) void attn_fa(const unsigned short* __restrict__ Q,
                                               const unsigned short* __restrict__ Kh,
                                               const unsigned short* __restrict__ Vt,
                                               const int* __restrict__ mask,
                                               unsigned short* __restrict__ ctx) {
    __shared__ __align__(16) unsigned short Ql[64][72];
    __shared__ __align__(16) float mb[SEQ];
    __shared__ __align__(16) unsigned short Kl[64][72];
    __shared__ __align__(16) unsigned short Vl[64][68];
    __shared__ __align__(16) float Op[2][32][32]; // epilogue partials, per d-half
    __shared__ __align__(16) float lp[2][32];     // kh=1 partial row sums
    int tid = threadIdx.x;
    int wave = tid >> 6, lane = tid & 63;
    int l31 = lane & 31, hi = lane >> 5;
    int qh = wave & 1, kh = wave >> 1; // q-half, key-half
    int bh = blockIdx.y, b = bh / H_, h = bh % H_;
    int q0 = blockIdx.x * 64;

    { // stage Q tile (64x64) once
        int row = tid >> 2, cb = (tid & 3) * 16;
        const unsigned short* gq = Q + ((size_t)bh * SEQ + q0 + row) * DK_ + cb;
        *(uint4*)&Ql[row][cb]     = *(const uint4*)gq;
        *(uint4*)&Ql[row][cb + 8] = *(const uint4*)(gq + 8);
    }
    { // mask -> additive bias in LDS (once per block)
        const int* mp = mask + (size_t)b * SEQ + tid * 8;
        int4 m0_ = *(const int4*)mp;
        int4 m1_ = *(const int4*)(mp + 4);
        float4 f0, f1;
        f0.x = m0_.x ? 0.f : -1e9f; f0.y = m0_.y ? 0.f : -1e9f;
        f0.z = m0_.z ? 0.f : -1e9f; f0.w = m0_.w ? 0.f : -1e9f;
        f1.x = m1_.x ? 0.f : -1e9f; f1.y = m1_.y ? 0.f : -1e9f;
        f1.z = m1_.z ? 0.f : -1e9f; f1.w = m1_.w ? 0.f : -1e9f;
        *(float4*)&mb[tid * 8] = f0;
        *(float4*)&mb[tid * 8 + 4] = f1;
    }
    __syncthreads(); // Ql/mb staged

    // loop-invariant Q fragments (queries 32*qh + l31)
    bf16x8 qf[4];
#pragma unroll
    for (int c = 0; c < 4; c++)
        qf[c] = *(const bf16x8*)&Ql[32 * qh + l31][16 * c + 8 * hi];

    float lrow = 0.f; // per-lane (q = l31) partial row sum over this wave's keys
    f32x16 o[2][2];   // [d-half][ilp]; summed at end
#pragma unroll
    for (int dt = 0; dt < 2; dt++)
#pragma unroll
        for (int p = 0; p < 2; p++)
#pragma unroll
            for (int r = 0; r < 16; r++) o[dt][p][r] = 0.f;

    int krow = tid >> 2, kcb = (tid & 3) * 16;
    const unsigned short* gk = Kh + ((size_t)bh * SEQ + krow) * DK_ + kcb;
    const unsigned short* gv = Vt + ((size_t)bh * DK_ + krow) * SEQ + kcb;

    // prefetch iter 0
    uint4 kr0 = *(const uint4*)gk, kr1 = *(const uint4*)(gk + 8);
    uint4 vr0 = *(const uint4*)gv, vr1 = *(const uint4*)(gv + 8);

    for (int kt = 0; kt < SEQ / 64; kt++) {
        __syncthreads(); // prev iter's K/V LDS reads done
        *(uint4*)&Kl[krow][kcb]     = kr0;
        *(uint4*)&Kl[krow][kcb + 8] = kr1;
        *(uint4*)&Vl[krow][kcb]     = vr0;
        *(uint4*)&Vl[krow][kcb + 8] = vr1;
        __syncthreads(); // tiles visible
        if (kt + 1 < SEQ / 64) { // prefetch next (latency hidden under compute)
            gk += (size_t)64 * DK_;
            gv += 64;
            kr0 = *(const uint4*)gk; kr1 = *(const uint4*)(gk + 8);
            vr0 = *(const uint4*)gv; vr1 = *(const uint4*)(gv + 8);
        }

        int kbase = 64 * kt + 32 * kh;
        // S^T = K.Q^T + maskbias (32 keys x 32 queries for this wave)
        f32x16 sT;
#pragma unroll
        for (int c = 0; c < 4; c++) {
            f32x4 mv = *(const f32x4*)&mb[kbase + 8 * c + 4 * hi];
#pragma unroll
            for (int j = 0; j < 4; j++) sT[4 * c + j] = mv[j];
        }
#pragma unroll
        for (int c = 0; c < 4; c++) {
            bf16x8 kf = *(const bf16x8*)&Kl[32 * kh + l31][16 * c + 8 * hi];
            sT = __builtin_amdgcn_mfma_f32_32x32x16_bf16(kf, qf[c], sT, 0, 0, 0);
        }

        // p = exp(s/8): regs ARE the A-operand of the 32x32x8 PV MFMA
        bf16x4 pfrag[4];
#pragma unroll
        for (int c = 0; c < 4; c++) {
            float p0 = __expf(sT[4 * c + 0] * 0.125f);
            float p1 = __expf(sT[4 * c + 1] * 0.125f);
            float p2 = __expf(sT[4 * c + 2] * 0.125f);
            float p3 = __expf(sT[4 * c + 3] * 0.125f);
            lrow += (p0 + p1) + (p2 + p3);
            union { unsigned u[2]; bf16x4 v; } pk;
            pk.u[0] = pack2bf(p0, p1);
            pk.u[1] = pack2bf(p2, p3);
            pfrag[c] = pk.v;
        }

        // O[q][d] += P.V over this wave's 32 keys
#pragma unroll
        for (int dt = 0; dt < 2; dt++)
#pragma unroll
            for (int c = 0; c < 4; c++) {
                bf16x4 vf = *(const bf16x4*)&Vl[32 * dt + l31][32 * kh + 8 * c + 4 * hi];
                o[dt][c & 1] = mfma32x8(pfrag[c], vf, o[dt][c & 1]);
            }
    }

    // combine across key-half wave pairs (two d-half chunks through Op), store
    lrow += __shfl_xor(lrow, 32); // both hi-halves hold full partial for q=l31
    float inv = 0.f;
#pragma unroll
    for (int dt = 0; dt < 2; dt++) {
        if (kh == 1) {
#pragma unroll
            for (int r = 0; r < 16; r++) {
                int qrl = (r & 3) + 8 * (r >> 2) + 4 * hi;
                Op[qh][qrl][l31] = o[dt][0][r] + o[dt][1][r];
            }
            if (dt == 0 && hi == 0) lp[qh][l31] = lrow;
        }
        __syncthreads();
        if (kh == 0) {
            if (dt == 0) {
                float l = lrow + lp[qh][l31];
                inv = l > 0.f ? 1.f / l : 0.f;
            }
#pragma unroll
            for (int r = 0; r < 16; r++) {
                int qrl = (r & 3) + 8 * (r >> 2) + 4 * hi;
                float invr = __shfl(inv, qrl); // inv lives at lane q
                int qg = q0 + 32 * qh + qrl;
                size_t base = ((size_t)b * SEQ + qg) * DM + h * DK_;
                float v = o[dt][0][r] + o[dt][1][r] + Op[qh][qrl][l31];
                ctx[base + 32 * dt + l31] = f2bf(v * invr);
            }
        }
        __syncthreads(); // Op safe for next chunk
    }
}

extern "C" void kernel_launch(void* const* d_in, const int* in_sizes, int n_in,
                              void* d_out, int out_size, void* d_ws, size_t ws_size,
                              hipStream_t stream) {
    const float* q  = (const float*)d_in[0];
    const float* k  = (const float*)d_in[1];
    const float* v  = (const float*)d_in[2];
    const float* Wq = (const float*)d_in[3];
    const float* bq = (const float*)d_in[4];
    const float* Wk = (const float*)d_in[5];
    const float* bk = (const float*)d_in[6];
    const float* Wv = (const float*)d_in[7];
    const float* bv = (const float*)d_in[8];
    const float* Wo = (const float*)d_in[9];
    const float* bo = (const float*)d_in[10];
    const int* mask = (const int*)d_in[11];

    unsigned short* ws = (unsigned short*)d_ws;
    unsigned short* qb = ws;
    unsigned short* kb = ws + PER_IN;
    unsigned short* vb = ws + 2 * PER_IN;
    unsigned short* Qh = ws + 3 * PER_IN;
    unsigned short* Kh = ws + 4 * PER_IN;
    unsigned short* Vhn = ws + 5 * PER_IN;
    unsigned short* WtQKV = ws + 6 * PER_IN;
    unsigned short* WtO = WtQKV + (size_t)3 * DM * DM;
    unsigned short* Vt = vb;  // vb dead after QKV GEMM
    unsigned short* ctx = qb; // qb dead after QKV GEMM

    cvt3<<<dim3(PER_IN / 1024, 3), 256, 0, stream>>>(q, k, v, qb, kb, vb);
    transpose4<<<dim3(DM / 32, DM / 32, 4), dim3(32, 8), 0, stream>>>(Wq, Wk, Wv, Wo, WtQKV);

    gemm128<1><<<dim3(MROWS / 128, 3 * DM / 128), 256, 0, stream>>>(
        qb, kb, vb, WtQKV, bq, bk, bv, Qh, Kh, Vhn);

    transposeV<<<dim3(SEQ / 64, B_DIM * H_), 256, 0, stream>>>(Vhn, Vt);

    attn_fa<<<dim3(SEQ / 64, B_DIM * H_), 256, 0, stream>>>(Qh, Kh, Vt, mask, ctx);

    gemm128<0><<<dim3(MROWS / 128, DM / 128), 256, 0, stream>>>(
        ctx, ctx, ctx, WtO, bo, bo, bo, d_out, d_out, d_out);
}